// Round 8
// baseline (40.605 us; speedup 1.0000x reference)
//
#include <hip/hip_runtime.h>
#include <math.h>

#define MARGIN 0.2f
#define NEG_WEIGHT 0.5f

constexpr int Bc = 64, Nc = 16, Lc = 1024, DH = 64, Ac = 8;
constexpr int NSAMP = Bc * Ac;            // 512
constexpr int CHUNKS = 16;                // chunks per sample
constexpr int ROWS_PER_CHUNK = Lc / CHUNKS;  // 64 rows
constexpr int WPB = 4;                    // waves (tasks) per block
constexpr int GRID = NSAMP * CHUNKS / WPB;   // 2048 blocks

__device__ __forceinline__ float fast_acosh(float z) {
    // z >= 1 + 1e-7 guaranteed by clamp
    return __logf(z + __builtin_sqrtf(z * z - 1.0f));
}

__device__ __forceinline__ float pdist(float x2, float y2, float d2) {
    x2 = fminf(x2, 0.999999f);
    y2 = fminf(y2, 0.999999f);
    float num = 2.0f * d2;
    float den = (1.0f - x2) * (1.0f - y2);
    float ratio = num * __builtin_amdgcn_rcpf(fmaxf(den, 1e-15f));
    float z = 1.0f + fmaxf(ratio, 1.0f + 1e-7f);
    return fast_acosh(z);
}

// Identical to R7. This round's experiment is in kernel_launch: the sample
// kernel is launched TWICE (idempotent writes) to measure the marginal cost
// of one steady-state sample pass vs fixed overhead.
__global__ __launch_bounds__(256) void sample_kernel(
    const float* __restrict__ h_curr,
    const float* __restrict__ demo_h,
    const int*   __restrict__ align_idx,
    const int*   __restrict__ lookahead_p,
    float* __restrict__ ws)
{
    const int tid  = threadIdx.x;
    const int task = blockIdx.x * WPB + (tid >> 6);
    const int s    = task >> 4;        // sample 0..511
    const int c    = task & 15;        // chunk  0..15
    const int b    = s >> 3;           // s / Ac
    const int lane = tid & 63;
    const int quad = lane & 3;
    const int rg   = lane >> 2;        // 0..15

    const int n0 = align_idx[s * 2 + 0];
    const int l0 = align_idx[s * 2 + 1];
    const int lk = lookahead_p[0];
    const int lt = l0 + lk;
    const bool valid = (lt >= 0) && (lt < Lc);

    if (!valid) {
        if (lane == 0) {
            float* wneg = ws + (size_t)(s * CHUNKS + c) * 2;
            wneg[0] = 0.0f; wneg[1] = 0.0f;
            if (c == 0) {
                float* wpos = ws + (size_t)NSAMP * CHUNKS * 2 + (size_t)s * 2;
                wpos[0] = 0.0f; wpos[1] = 0.0f;
            }
        }
        return;
    }

    // chunks whose rows are all <= lt contribute nothing — skip the 16 KB read
    const bool dead = (c * ROWS_PER_CHUNK + (ROWS_PER_CHUNK - 1)) <= lt;
    if (dead && c != 0) {
        if (lane == 0) {
            float* wneg = ws + (size_t)(s * CHUNKS + c) * 2;
            wneg[0] = 0.0f; wneg[1] = 0.0f;
        }
        return;
    }

    const int lt_c = min(max(lt, 0), Lc - 1);

    const float* __restrict__ xrow = h_curr + (size_t)b * DH + quad * 16;
    const float* __restrict__ seq  = demo_h + (((size_t)b * Nc + (size_t)n0) * Lc) * DH;

    // x fragment: 16 dims per lane
    float4 xv[4];
    #pragma unroll
    for (int j = 0; j < 4; ++j)
        xv[j] = *reinterpret_cast<const float4*>(xrow + j * 4);

    float x2 = 0.0f;
    #pragma unroll
    for (int j = 0; j < 4; ++j) {
        x2 = fmaf(xv[j].x, xv[j].x, x2);
        x2 = fmaf(xv[j].y, xv[j].y, x2);
        x2 = fmaf(xv[j].z, xv[j].z, x2);
        x2 = fmaf(xv[j].w, xv[j].w, x2);
    }
    x2 += __shfl_xor(x2, 1, 64);
    x2 += __shfl_xor(x2, 2, 64);   // x2 valid in all lanes of each quad-group

    // d_pos from row lt_c
    float d_pos;
    {
        const float* rowp = seq + (size_t)lt_c * DH + quad * 16;
        float d2 = 0.0f, y2 = 0.0f;
        #pragma unroll
        for (int j = 0; j < 4; ++j) {
            float4 yv = *reinterpret_cast<const float4*>(rowp + j * 4);
            float dx = xv[j].x - yv.x, dy = xv[j].y - yv.y;
            float dz = xv[j].z - yv.z, dw = xv[j].w - yv.w;
            d2 = fmaf(dx, dx, d2); d2 = fmaf(dy, dy, d2);
            d2 = fmaf(dz, dz, d2); d2 = fmaf(dw, dw, d2);
            y2 = fmaf(yv.x, yv.x, y2); y2 = fmaf(yv.y, yv.y, y2);
            y2 = fmaf(yv.z, yv.z, y2); y2 = fmaf(yv.w, yv.w, y2);
        }
        d2 += __shfl_xor(d2, 1, 64); d2 += __shfl_xor(d2, 2, 64);
        y2 += __shfl_xor(y2, 1, 64); y2 += __shfl_xor(y2, 2, 64);
        d_pos = pdist(x2, y2, d2);
    }

    if (dead) {   // only possible for c == 0: write d_pos, zero hinge, exit
        if (lane == 0) {
            float* wneg = ws + (size_t)(s * CHUNKS + c) * 2;
            wneg[0] = 0.0f; wneg[1] = 0.0f;
            float* wpos = ws + (size_t)NSAMP * CHUNKS * 2 + (size_t)s * 2;
            wpos[0] = d_pos; wpos[1] = 1.0f;
        }
        return;
    }

    // negatives: 64 rows of this chunk, 16 rows per pass (one per row-group)
    float hinge_acc = 0.0f, cnt_acc = 0.0f;
    #pragma unroll
    for (int it = 0; it < 4; ++it) {
        const int row = c * ROWS_PER_CHUNK + it * 16 + rg;
        const float* rowp = seq + (size_t)row * DH + quad * 16;
        float d2 = 0.0f, y2 = 0.0f;
        #pragma unroll
        for (int j = 0; j < 4; ++j) {
            float4 yv = *reinterpret_cast<const float4*>(rowp + j * 4);
            float dx = xv[j].x - yv.x, dy = xv[j].y - yv.y;
            float dz = xv[j].z - yv.z, dw = xv[j].w - yv.w;
            d2 = fmaf(dx, dx, d2); d2 = fmaf(dy, dy, d2);
            d2 = fmaf(dz, dz, d2); d2 = fmaf(dw, dw, d2);
            y2 = fmaf(yv.x, yv.x, y2); y2 = fmaf(yv.y, yv.y, y2);
            y2 = fmaf(yv.z, yv.z, y2); y2 = fmaf(yv.w, yv.w, y2);
        }
        d2 += __shfl_xor(d2, 1, 64); d2 += __shfl_xor(d2, 2, 64);
        y2 += __shfl_xor(y2, 1, 64); y2 += __shfl_xor(y2, 2, 64);
        float dneg = pdist(x2, y2, d2);
        if (row > lt) {
            hinge_acc += fmaxf(MARGIN - dneg + d_pos, 0.0f);
            cnt_acc   += 1.0f;
        }
    }

    // values are uniform within each quad; sum across the 16 row-groups only
    #pragma unroll
    for (int m = 4; m < 64; m <<= 1) {
        hinge_acc += __shfl_xor(hinge_acc, m, 64);
        cnt_acc   += __shfl_xor(cnt_acc,   m, 64);
    }

    if (lane == 0) {
        float* wneg = ws + (size_t)(s * CHUNKS + c) * 2;
        wneg[0] = hinge_acc;
        wneg[1] = cnt_acc;
        if (c == 0) {
            float* wpos = ws + (size_t)NSAMP * CHUNKS * 2 + (size_t)s * 2;
            wpos[0] = d_pos; wpos[1] = 1.0f;
        }
    }
}

__global__ __launch_bounds__(256) void reduce_kernel(
    const float* __restrict__ ws, float* __restrict__ out)
{
    const int tid = threadIdx.x;
    float pn = 0.0f, pv = 0.0f, nn = 0.0f, nc = 0.0f;
    for (int s = tid; s < NSAMP; s += 256) {
        float h = 0.0f, ct = 0.0f;
        #pragma unroll
        for (int c = 0; c < CHUNKS; ++c) {
            h  += ws[(size_t)(s * CHUNKS + c) * 2 + 0];
            ct += ws[(size_t)(s * CHUNKS + c) * 2 + 1];
        }
        float per_sample = h / fmaxf(ct, 1.0f);
        float has_neg = (ct > 0.0f) ? 1.0f : 0.0f;
        nn += per_sample * has_neg;
        nc += has_neg;
        pn += ws[(size_t)NSAMP * CHUNKS * 2 + (size_t)s * 2 + 0];
        pv += ws[(size_t)NSAMP * CHUNKS * 2 + (size_t)s * 2 + 1];
    }
    __shared__ float4 sh[256];
    sh[tid] = make_float4(pn, pv, nn, nc);
    __syncthreads();
    for (int off = 128; off > 0; off >>= 1) {
        if (tid < off) {
            sh[tid].x += sh[tid + off].x;
            sh[tid].y += sh[tid + off].y;
            sh[tid].z += sh[tid + off].z;
            sh[tid].w += sh[tid + off].w;
        }
        __syncthreads();
    }
    if (tid == 0) {
        float pos_term = sh[0].x / fmaxf(sh[0].y, 1.0f);
        float neg_term = sh[0].z / fmaxf(sh[0].w, 1.0f);
        out[0] = pos_term + NEG_WEIGHT * neg_term;
    }
}

extern "C" void kernel_launch(void* const* d_in, const int* in_sizes, int n_in,
                              void* d_out, int out_size, void* d_ws, size_t ws_size,
                              hipStream_t stream) {
    const float* h_curr    = (const float*)d_in[0];
    const float* demo_h    = (const float*)d_in[1];
    const int*   align_idx = (const int*)d_in[2];
    const int*   lookahead = (const int*)d_in[3];
    float* out = (float*)d_out;
    float* ws  = (float*)d_ws;

    // MEASUREMENT ROUND: sample_kernel launched twice (idempotent, identical
    // writes). dur(R8) - dur(R7) = marginal cost of one steady-state sample
    // pass, separating in-kernel time from fixed launch/reduce overhead.
    sample_kernel<<<GRID, 256, 0, stream>>>(h_curr, demo_h, align_idx, lookahead, ws);
    sample_kernel<<<GRID, 256, 0, stream>>>(h_curr, demo_h, align_idx, lookahead, ws);
    reduce_kernel<<<1, 256, 0, stream>>>(ws, out);
}

// Round 9
// 33.654 us; speedup vs baseline: 1.2066x; 1.2066x over previous
//
#include <hip/hip_runtime.h>
#include <math.h>

#define MARGIN 0.2f
#define NEG_WEIGHT 0.5f

constexpr int Bc = 64, Nc = 16, Lc = 1024, DH = 64, Ac = 8;
constexpr int NSAMP = Bc * Ac;            // 512
constexpr int CHUNKS = 16;                // chunks per sample
constexpr int RPC = Lc / CHUNKS;          // 64 rows per chunk
constexpr int WPB = 4;                    // wave-tasks per 256-thread block
constexpr int GRID = NSAMP * CHUNKS / WPB;   // 2048 blocks

__device__ __forceinline__ float fast_acosh(float z) {
    // z >= 1 + 1e-7 guaranteed by clamp
    return __logf(z + __builtin_sqrtf(z * z - 1.0f));
}

__device__ __forceinline__ float pdist(float x2, float y2, float d2) {
    x2 = fminf(x2, 0.999999f);
    y2 = fminf(y2, 0.999999f);
    float num = 2.0f * d2;
    float den = (1.0f - x2) * (1.0f - y2);
    float ratio = num * __builtin_amdgcn_rcpf(fmaxf(den, 1e-15f));
    float z = 1.0f + fmaxf(ratio, 1.0f + 1e-7f);
    return fast_acosh(z);
}

// R7 grid/packing. Phase 1 (d_pos): quad layout, unchanged from R7.
// Phase 2 (negatives): ONE LANE PER ROW — no shuffles in the hot loop,
// one vectorized pdist per task, deep load pipelining.
__global__ __launch_bounds__(256) void sample_kernel(
    const float* __restrict__ h_curr,
    const float* __restrict__ demo_h,
    const int*   __restrict__ align_idx,
    const int*   __restrict__ lookahead_p,
    float* __restrict__ ws)
{
    const int tid  = threadIdx.x;
    const int task = blockIdx.x * WPB + (tid >> 6);
    const int s    = task >> 4;        // sample 0..511
    const int c    = task & 15;        // chunk  0..15
    const int b    = s >> 3;           // s / Ac
    const int lane = tid & 63;
    const int quad = lane & 3;

    const int n0 = align_idx[s * 2 + 0];
    const int l0 = align_idx[s * 2 + 1];
    const int lk = lookahead_p[0];
    const int lt = l0 + lk;
    const bool valid = (lt >= 0) && (lt < Lc);

    if (!valid) {
        if (lane == 0) {
            float* wneg = ws + (size_t)(s * CHUNKS + c) * 2;
            wneg[0] = 0.0f; wneg[1] = 0.0f;
            if (c == 0) {
                float* wpos = ws + (size_t)NSAMP * CHUNKS * 2 + (size_t)s * 2;
                wpos[0] = 0.0f; wpos[1] = 0.0f;
            }
        }
        return;
    }

    // chunks whose rows are all <= lt contribute nothing — skip the 16 KB read
    const bool dead = (c * RPC + (RPC - 1)) <= lt;
    if (dead && c != 0) {
        if (lane == 0) {
            float* wneg = ws + (size_t)(s * CHUNKS + c) * 2;
            wneg[0] = 0.0f; wneg[1] = 0.0f;
        }
        return;
    }

    const int lt_c = min(max(lt, 0), Lc - 1);

    const float* __restrict__ xrow_q = h_curr + (size_t)b * DH + quad * 16;
    const float* __restrict__ xrow   = h_curr + (size_t)b * DH;
    const float* __restrict__ seq    = demo_h + (((size_t)b * Nc + (size_t)n0) * Lc) * DH;

    // ---------- phase 1: d_pos (quad layout, as in R7) ----------
    float4 xv[4];
    #pragma unroll
    for (int j = 0; j < 4; ++j)
        xv[j] = *reinterpret_cast<const float4*>(xrow_q + j * 4);

    float x2 = 0.0f;
    #pragma unroll
    for (int j = 0; j < 4; ++j) {
        x2 = fmaf(xv[j].x, xv[j].x, x2);
        x2 = fmaf(xv[j].y, xv[j].y, x2);
        x2 = fmaf(xv[j].z, xv[j].z, x2);
        x2 = fmaf(xv[j].w, xv[j].w, x2);
    }
    x2 += __shfl_xor(x2, 1, 64);
    x2 += __shfl_xor(x2, 2, 64);   // wave-uniform within each quad-group

    float d_pos;
    {
        const float* rowp = seq + (size_t)lt_c * DH + quad * 16;
        float d2 = 0.0f, y2 = 0.0f;
        #pragma unroll
        for (int j = 0; j < 4; ++j) {
            float4 yv = *reinterpret_cast<const float4*>(rowp + j * 4);
            float dx = xv[j].x - yv.x, dy = xv[j].y - yv.y;
            float dz = xv[j].z - yv.z, dw = xv[j].w - yv.w;
            d2 = fmaf(dx, dx, d2); d2 = fmaf(dy, dy, d2);
            d2 = fmaf(dz, dz, d2); d2 = fmaf(dw, dw, d2);
            y2 = fmaf(yv.x, yv.x, y2); y2 = fmaf(yv.y, yv.y, y2);
            y2 = fmaf(yv.z, yv.z, y2); y2 = fmaf(yv.w, yv.w, y2);
        }
        d2 += __shfl_xor(d2, 1, 64); d2 += __shfl_xor(d2, 2, 64);
        y2 += __shfl_xor(y2, 1, 64); y2 += __shfl_xor(y2, 2, 64);
        d_pos = pdist(x2, y2, d2);
    }

    if (dead) {   // only possible for c == 0: write d_pos, zero hinge, exit
        if (lane == 0) {
            float* wneg = ws + (size_t)(s * CHUNKS + c) * 2;
            wneg[0] = 0.0f; wneg[1] = 0.0f;
            float* wpos = ws + (size_t)NSAMP * CHUNKS * 2 + (size_t)s * 2;
            wpos[0] = d_pos; wpos[1] = 1.0f;
        }
        return;
    }

    // ---------- phase 2: negatives, one lane per row ----------
    const int row = c * RPC + lane;               // this lane's row
    const float* __restrict__ rowp = seq + (size_t)row * DH;
    const float ma = MARGIN + d_pos;

    float d2a = 0.0f, d2b = 0.0f, y2a = 0.0f, y2b = 0.0f;
    #pragma unroll 2
    for (int dd = 0; dd < 4; ++dd) {
        // x block: wave-uniform addresses -> broadcast loads
        float4 xb0 = *reinterpret_cast<const float4*>(xrow + dd * 16 + 0);
        float4 xb1 = *reinterpret_cast<const float4*>(xrow + dd * 16 + 4);
        float4 xb2 = *reinterpret_cast<const float4*>(xrow + dd * 16 + 8);
        float4 xb3 = *reinterpret_cast<const float4*>(xrow + dd * 16 + 12);
        // y block: per-lane row
        float4 yb0 = *reinterpret_cast<const float4*>(rowp + dd * 16 + 0);
        float4 yb1 = *reinterpret_cast<const float4*>(rowp + dd * 16 + 4);
        float4 yb2 = *reinterpret_cast<const float4*>(rowp + dd * 16 + 8);
        float4 yb3 = *reinterpret_cast<const float4*>(rowp + dd * 16 + 12);

        float dx;
        dx = xb0.x - yb0.x; d2a = fmaf(dx, dx, d2a); y2a = fmaf(yb0.x, yb0.x, y2a);
        dx = xb0.y - yb0.y; d2b = fmaf(dx, dx, d2b); y2b = fmaf(yb0.y, yb0.y, y2b);
        dx = xb0.z - yb0.z; d2a = fmaf(dx, dx, d2a); y2a = fmaf(yb0.z, yb0.z, y2a);
        dx = xb0.w - yb0.w; d2b = fmaf(dx, dx, d2b); y2b = fmaf(yb0.w, yb0.w, y2b);
        dx = xb1.x - yb1.x; d2a = fmaf(dx, dx, d2a); y2a = fmaf(yb1.x, yb1.x, y2a);
        dx = xb1.y - yb1.y; d2b = fmaf(dx, dx, d2b); y2b = fmaf(yb1.y, yb1.y, y2b);
        dx = xb1.z - yb1.z; d2a = fmaf(dx, dx, d2a); y2a = fmaf(yb1.z, yb1.z, y2a);
        dx = xb1.w - yb1.w; d2b = fmaf(dx, dx, d2b); y2b = fmaf(yb1.w, yb1.w, y2b);
        dx = xb2.x - yb2.x; d2a = fmaf(dx, dx, d2a); y2a = fmaf(yb2.x, yb2.x, y2a);
        dx = xb2.y - yb2.y; d2b = fmaf(dx, dx, d2b); y2b = fmaf(yb2.y, yb2.y, y2b);
        dx = xb2.z - yb2.z; d2a = fmaf(dx, dx, d2a); y2a = fmaf(yb2.z, yb2.z, y2a);
        dx = xb2.w - yb2.w; d2b = fmaf(dx, dx, d2b); y2b = fmaf(yb2.w, yb2.w, y2b);
        dx = xb3.x - yb3.x; d2a = fmaf(dx, dx, d2a); y2a = fmaf(yb3.x, yb3.x, y2a);
        dx = xb3.y - yb3.y; d2b = fmaf(dx, dx, d2b); y2b = fmaf(yb3.y, yb3.y, y2b);
        dx = xb3.z - yb3.z; d2a = fmaf(dx, dx, d2a); y2a = fmaf(yb3.z, yb3.z, y2a);
        dx = xb3.w - yb3.w; d2b = fmaf(dx, dx, d2b); y2b = fmaf(yb3.w, yb3.w, y2b);
    }
    const float d2 = d2a + d2b;
    const float y2 = y2a + y2b;

    const float dneg = pdist(x2, y2, d2);
    float h = ((row > lt) ? fmaxf(ma - dneg, 0.0f) : 0.0f);

    // butterfly sum across all 64 lanes (once per task)
    #pragma unroll
    for (int m = 1; m < 64; m <<= 1)
        h += __shfl_xor(h, m, 64);

    if (lane == 0) {
        // closed-form count of rows > lt in this chunk (live => >= 1)
        const int cnt = (c + 1) * RPC - max(c * RPC, lt + 1);
        float* wneg = ws + (size_t)(s * CHUNKS + c) * 2;
        wneg[0] = h;
        wneg[1] = (float)cnt;
        if (c == 0) {
            float* wpos = ws + (size_t)NSAMP * CHUNKS * 2 + (size_t)s * 2;
            wpos[0] = d_pos; wpos[1] = 1.0f;
        }
    }
}

__global__ __launch_bounds__(256) void reduce_kernel(
    const float* __restrict__ ws, float* __restrict__ out)
{
    const int tid = threadIdx.x;
    float pn = 0.0f, pv = 0.0f, nn = 0.0f, nc = 0.0f;
    for (int s = tid; s < NSAMP; s += 256) {
        float h = 0.0f, ct = 0.0f;
        #pragma unroll
        for (int c = 0; c < CHUNKS; ++c) {
            h  += ws[(size_t)(s * CHUNKS + c) * 2 + 0];
            ct += ws[(size_t)(s * CHUNKS + c) * 2 + 1];
        }
        float per_sample = h / fmaxf(ct, 1.0f);
        float has_neg = (ct > 0.0f) ? 1.0f : 0.0f;
        nn += per_sample * has_neg;
        nc += has_neg;
        pn += ws[(size_t)NSAMP * CHUNKS * 2 + (size_t)s * 2 + 0];
        pv += ws[(size_t)NSAMP * CHUNKS * 2 + (size_t)s * 2 + 1];
    }
    __shared__ float4 sh[256];
    sh[tid] = make_float4(pn, pv, nn, nc);
    __syncthreads();
    for (int off = 128; off > 0; off >>= 1) {
        if (tid < off) {
            sh[tid].x += sh[tid + off].x;
            sh[tid].y += sh[tid + off].y;
            sh[tid].z += sh[tid + off].z;
            sh[tid].w += sh[tid + off].w;
        }
        __syncthreads();
    }
    if (tid == 0) {
        float pos_term = sh[0].x / fmaxf(sh[0].y, 1.0f);
        float neg_term = sh[0].z / fmaxf(sh[0].w, 1.0f);
        out[0] = pos_term + NEG_WEIGHT * neg_term;
    }
}

extern "C" void kernel_launch(void* const* d_in, const int* in_sizes, int n_in,
                              void* d_out, int out_size, void* d_ws, size_t ws_size,
                              hipStream_t stream) {
    const float* h_curr    = (const float*)d_in[0];
    const float* demo_h    = (const float*)d_in[1];
    const int*   align_idx = (const int*)d_in[2];
    const int*   lookahead = (const int*)d_in[3];
    float* out = (float*)d_out;
    float* ws  = (float*)d_ws;

    sample_kernel<<<GRID, 256, 0, stream>>>(h_curr, demo_h, align_idx, lookahead, ws);
    reduce_kernel<<<1, 256, 0, stream>>>(ws, out);
}

// Round 10
// 26.882 us; speedup vs baseline: 1.5105x; 1.2519x over previous
//
#include <hip/hip_runtime.h>
#include <math.h>

#define MARGIN 0.2f
#define NEG_WEIGHT 0.5f

constexpr int Bc = 64, Nc = 16, Lc = 1024, DH = 64, Ac = 8;
constexpr int NSAMP = Bc * Ac;            // 512
constexpr int CHUNKS = 16;                // chunks per sample
constexpr int RPC = Lc / CHUNKS;          // 64 rows per chunk
constexpr int WPB = 4;                    // wave-tasks per 256-thread block
constexpr int GRID = NSAMP * CHUNKS / WPB;   // 2048 blocks

__device__ __forceinline__ float fast_acosh(float z) {
    // z >= 1 + 1e-7 guaranteed by clamp
    return __logf(z + __builtin_sqrtf(z * z - 1.0f));
}

__device__ __forceinline__ float pdist(float x2, float y2, float d2) {
    x2 = fminf(x2, 0.999999f);
    y2 = fminf(y2, 0.999999f);
    float num = 2.0f * d2;
    float den = (1.0f - x2) * (1.0f - y2);
    float ratio = num * __builtin_amdgcn_rcpf(fmaxf(den, 1e-15f));
    float z = 1.0f + fmaxf(ratio, 1.0f + 1e-7f);
    return fast_acosh(z);
}

// R7 grid/packing/skip. ONE change: coalesced 16-lanes-per-row layout.
// gl = lane&15 owns float4 gl of a row (contiguous 16 B per lane -> a wave's
// load = 1 KB over 16 fully-covered cache lines); rg = lane>>4 owns one of
// 4 rows per iteration. Row-reduce: 4-step butterfly within 16-lane groups.
__global__ __launch_bounds__(256) void sample_kernel(
    const float* __restrict__ h_curr,
    const float* __restrict__ demo_h,
    const int*   __restrict__ align_idx,
    const int*   __restrict__ lookahead_p,
    float* __restrict__ ws)
{
    const int tid  = threadIdx.x;
    const int task = blockIdx.x * WPB + (tid >> 6);
    const int s    = task >> 4;        // sample 0..511
    const int c    = task & 15;        // chunk  0..15
    const int b    = s >> 3;           // s / Ac
    const int lane = tid & 63;
    const int gl   = lane & 15;        // float4 index within a row
    const int rg   = lane >> 4;        // 0..3 row within an iteration

    const int n0 = align_idx[s * 2 + 0];
    const int l0 = align_idx[s * 2 + 1];
    const int lk = lookahead_p[0];
    const int lt = l0 + lk;
    const bool valid = (lt >= 0) && (lt < Lc);

    if (!valid) {
        if (lane == 0) {
            float* wneg = ws + (size_t)(s * CHUNKS + c) * 2;
            wneg[0] = 0.0f; wneg[1] = 0.0f;
            if (c == 0) {
                float* wpos = ws + (size_t)NSAMP * CHUNKS * 2 + (size_t)s * 2;
                wpos[0] = 0.0f; wpos[1] = 0.0f;
            }
        }
        return;
    }

    // chunks whose rows are all <= lt contribute nothing — skip the 16 KB read
    const bool dead = (c * RPC + (RPC - 1)) <= lt;
    if (dead && c != 0) {
        if (lane == 0) {
            float* wneg = ws + (size_t)(s * CHUNKS + c) * 2;
            wneg[0] = 0.0f; wneg[1] = 0.0f;
        }
        return;
    }

    const int lt_c = min(max(lt, 0), Lc - 1);

    const float* __restrict__ xrow = h_curr + (size_t)b * DH;
    const float* __restrict__ seq  = demo_h + (((size_t)b * Nc + (size_t)n0) * Lc) * DH;

    // x fragment: 4 dims per lane (float4 gl of the row)
    const float4 xq = *reinterpret_cast<const float4*>(xrow + gl * 4);
    float x2 = fmaf(xq.x, xq.x, fmaf(xq.y, xq.y, fmaf(xq.z, xq.z, xq.w * xq.w)));
    x2 += __shfl_xor(x2, 1, 64);
    x2 += __shfl_xor(x2, 2, 64);
    x2 += __shfl_xor(x2, 4, 64);
    x2 += __shfl_xor(x2, 8, 64);   // uniform within each 16-lane group

    // ---------- phase 1: d_pos (row lt_c, 16-lane coalesced) ----------
    float d_pos;
    {
        const float4 tv = *reinterpret_cast<const float4*>(seq + (size_t)lt_c * DH + gl * 4);
        float dx = xq.x - tv.x, dy = xq.y - tv.y, dz = xq.z - tv.z, dw = xq.w - tv.w;
        float d2 = fmaf(dx, dx, fmaf(dy, dy, fmaf(dz, dz, dw * dw)));
        float y2 = fmaf(tv.x, tv.x, fmaf(tv.y, tv.y, fmaf(tv.z, tv.z, tv.w * tv.w)));
        d2 += __shfl_xor(d2, 1, 64); d2 += __shfl_xor(d2, 2, 64);
        d2 += __shfl_xor(d2, 4, 64); d2 += __shfl_xor(d2, 8, 64);
        y2 += __shfl_xor(y2, 1, 64); y2 += __shfl_xor(y2, 2, 64);
        y2 += __shfl_xor(y2, 4, 64); y2 += __shfl_xor(y2, 8, 64);
        d_pos = pdist(x2, y2, d2);
    }

    if (dead) {   // only possible for c == 0: write d_pos, zero hinge, exit
        if (lane == 0) {
            float* wneg = ws + (size_t)(s * CHUNKS + c) * 2;
            wneg[0] = 0.0f; wneg[1] = 0.0f;
            float* wpos = ws + (size_t)NSAMP * CHUNKS * 2 + (size_t)s * 2;
            wpos[0] = d_pos; wpos[1] = 1.0f;
        }
        return;
    }

    // ---------- phase 2: negatives, 4 rows per iteration, 16 iterations ----------
    const float ma = MARGIN + d_pos;
    float h = 0.0f;
    #pragma unroll
    for (int it = 0; it < 16; ++it) {
        const int rowbase = c * RPC + it * 4;
        if (rowbase + 3 <= lt) continue;        // all 4 rows masked out
        const int row = rowbase + rg;
        const float4 yv = *reinterpret_cast<const float4*>(seq + (size_t)row * DH + gl * 4);
        float dx = xq.x - yv.x, dy = xq.y - yv.y, dz = xq.z - yv.z, dw = xq.w - yv.w;
        float d2 = fmaf(dx, dx, fmaf(dy, dy, fmaf(dz, dz, dw * dw)));
        float y2 = fmaf(yv.x, yv.x, fmaf(yv.y, yv.y, fmaf(yv.z, yv.z, yv.w * yv.w)));
        d2 += __shfl_xor(d2, 1, 64); d2 += __shfl_xor(d2, 2, 64);
        d2 += __shfl_xor(d2, 4, 64); d2 += __shfl_xor(d2, 8, 64);
        y2 += __shfl_xor(y2, 1, 64); y2 += __shfl_xor(y2, 2, 64);
        y2 += __shfl_xor(y2, 4, 64); y2 += __shfl_xor(y2, 8, 64);
        const float dneg = pdist(x2, y2, d2);
        h += (row > lt) ? fmaxf(ma - dneg, 0.0f) : 0.0f;
    }

    // h is uniform within each 16-lane group; sum the 4 groups
    h += __shfl_xor(h, 16, 64);
    h += __shfl_xor(h, 32, 64);

    if (lane == 0) {
        // closed-form count of rows > lt in this chunk (live => >= 1)
        const int cnt = (c + 1) * RPC - max(c * RPC, lt + 1);
        float* wneg = ws + (size_t)(s * CHUNKS + c) * 2;
        wneg[0] = h;
        wneg[1] = (float)cnt;
        if (c == 0) {
            float* wpos = ws + (size_t)NSAMP * CHUNKS * 2 + (size_t)s * 2;
            wpos[0] = d_pos; wpos[1] = 1.0f;
        }
    }
}

__global__ __launch_bounds__(256) void reduce_kernel(
    const float* __restrict__ ws, float* __restrict__ out)
{
    const int tid = threadIdx.x;
    float pn = 0.0f, pv = 0.0f, nn = 0.0f, nc = 0.0f;
    for (int s = tid; s < NSAMP; s += 256) {
        float h = 0.0f, ct = 0.0f;
        #pragma unroll
        for (int c = 0; c < CHUNKS; ++c) {
            h  += ws[(size_t)(s * CHUNKS + c) * 2 + 0];
            ct += ws[(size_t)(s * CHUNKS + c) * 2 + 1];
        }
        float per_sample = h / fmaxf(ct, 1.0f);
        float has_neg = (ct > 0.0f) ? 1.0f : 0.0f;
        nn += per_sample * has_neg;
        nc += has_neg;
        pn += ws[(size_t)NSAMP * CHUNKS * 2 + (size_t)s * 2 + 0];
        pv += ws[(size_t)NSAMP * CHUNKS * 2 + (size_t)s * 2 + 1];
    }
    __shared__ float4 sh[256];
    sh[tid] = make_float4(pn, pv, nn, nc);
    __syncthreads();
    for (int off = 128; off > 0; off >>= 1) {
        if (tid < off) {
            sh[tid].x += sh[tid + off].x;
            sh[tid].y += sh[tid + off].y;
            sh[tid].z += sh[tid + off].z;
            sh[tid].w += sh[tid + off].w;
        }
        __syncthreads();
    }
    if (tid == 0) {
        float pos_term = sh[0].x / fmaxf(sh[0].y, 1.0f);
        float neg_term = sh[0].z / fmaxf(sh[0].w, 1.0f);
        out[0] = pos_term + NEG_WEIGHT * neg_term;
    }
}

extern "C" void kernel_launch(void* const* d_in, const int* in_sizes, int n_in,
                              void* d_out, int out_size, void* d_ws, size_t ws_size,
                              hipStream_t stream) {
    const float* h_curr    = (const float*)d_in[0];
    const float* demo_h    = (const float*)d_in[1];
    const int*   align_idx = (const int*)d_in[2];
    const int*   lookahead = (const int*)d_in[3];
    float* out = (float*)d_out;
    float* ws  = (float*)d_ws;

    sample_kernel<<<GRID, 256, 0, stream>>>(h_curr, demo_h, align_idx, lookahead, ws);
    reduce_kernel<<<1, 256, 0, stream>>>(ws, out);
}

// Round 11
// 24.218 us; speedup vs baseline: 1.6767x; 1.1100x over previous
//
#include <hip/hip_runtime.h>
#include <math.h>

#define MARGIN 0.2f
#define NEG_WEIGHT 0.5f

constexpr int Bc = 64, Nc = 16, Lc = 1024, DH = 64, Ac = 8;
constexpr int NSAMP = Bc * Ac;            // 512
constexpr int CHUNKS = 16;                // chunks per sample
constexpr int RPC = Lc / CHUNKS;          // 64 rows per chunk
constexpr int WPB = 4;                    // wave-tasks per 256-thread block
constexpr int GRID = NSAMP * CHUNKS / WPB;   // 2048 blocks

__device__ __forceinline__ float fast_acosh(float z) {
    // z >= 1 + 1e-7 guaranteed by clamp
    return __logf(z + __builtin_sqrtf(z * z - 1.0f));
}

__device__ __forceinline__ float pdist(float x2, float y2, float d2) {
    x2 = fminf(x2, 0.999999f);
    y2 = fminf(y2, 0.999999f);
    float num = 2.0f * d2;
    float den = (1.0f - x2) * (1.0f - y2);
    float ratio = num * __builtin_amdgcn_rcpf(fmaxf(den, 1e-15f));
    float z = 1.0f + fmaxf(ratio, 1.0f + 1e-7f);
    return fast_acosh(z);
}

// R7 per-wave code. Changes vs R7:
//  (1) task = wave*2048 + blockIdx: a block's 4 waves come from 4 samples
//      128 apart -> live/dead tasks de-clustered (straggler reduction).
//  (2) wneg is a single float in [c][s] layout; cnt is closed-form in the
//      reduce (drops 4 shuffles/task here and halves ws traffic).
// lane layout: quad = lane&3 owns dims [quad*16,+16); rg = lane>>2 owns a row
__global__ __launch_bounds__(256) void sample_kernel(
    const float* __restrict__ h_curr,
    const float* __restrict__ demo_h,
    const int*   __restrict__ align_idx,
    const int*   __restrict__ lookahead_p,
    float* __restrict__ wneg,    // [CHUNKS][NSAMP] hinge sums
    float* __restrict__ wpos)    // [NSAMP] d_pos (0 if invalid)
{
    const int tid  = threadIdx.x;
    const int task = (tid >> 6) * GRID + blockIdx.x;   // de-clustered mapping
    const int s    = task >> 4;        // sample 0..511
    const int c    = task & 15;        // chunk  0..15
    const int b    = s >> 3;           // s / Ac
    const int lane = tid & 63;
    const int quad = lane & 3;
    const int rg   = lane >> 2;        // 0..15

    const int n0 = align_idx[s * 2 + 0];
    const int l0 = align_idx[s * 2 + 1];
    const int lk = lookahead_p[0];
    const int lt = l0 + lk;
    const bool valid = (lt >= 0) && (lt < Lc);

    if (!valid) {
        if (lane == 0) {
            wneg[c * NSAMP + s] = 0.0f;
            if (c == 0) wpos[s] = 0.0f;
        }
        return;
    }

    // chunks whose rows are all <= lt contribute nothing — skip the 16 KB read
    const bool dead = (c * RPC + (RPC - 1)) <= lt;
    if (dead && c != 0) {
        if (lane == 0) wneg[c * NSAMP + s] = 0.0f;
        return;
    }

    const int lt_c = min(max(lt, 0), Lc - 1);

    const float* __restrict__ xrow = h_curr + (size_t)b * DH + quad * 16;
    const float* __restrict__ seq  = demo_h + (((size_t)b * Nc + (size_t)n0) * Lc) * DH;

    // x fragment: 16 dims per lane
    float4 xv[4];
    #pragma unroll
    for (int j = 0; j < 4; ++j)
        xv[j] = *reinterpret_cast<const float4*>(xrow + j * 4);

    float x2 = 0.0f;
    #pragma unroll
    for (int j = 0; j < 4; ++j) {
        x2 = fmaf(xv[j].x, xv[j].x, x2);
        x2 = fmaf(xv[j].y, xv[j].y, x2);
        x2 = fmaf(xv[j].z, xv[j].z, x2);
        x2 = fmaf(xv[j].w, xv[j].w, x2);
    }
    x2 += __shfl_xor(x2, 1, 64);
    x2 += __shfl_xor(x2, 2, 64);   // uniform within each quad-group

    // d_pos from row lt_c
    float d_pos;
    {
        const float* rowp = seq + (size_t)lt_c * DH + quad * 16;
        float d2 = 0.0f, y2 = 0.0f;
        #pragma unroll
        for (int j = 0; j < 4; ++j) {
            float4 yv = *reinterpret_cast<const float4*>(rowp + j * 4);
            float dx = xv[j].x - yv.x, dy = xv[j].y - yv.y;
            float dz = xv[j].z - yv.z, dw = xv[j].w - yv.w;
            d2 = fmaf(dx, dx, d2); d2 = fmaf(dy, dy, d2);
            d2 = fmaf(dz, dz, d2); d2 = fmaf(dw, dw, d2);
            y2 = fmaf(yv.x, yv.x, y2); y2 = fmaf(yv.y, yv.y, y2);
            y2 = fmaf(yv.z, yv.z, y2); y2 = fmaf(yv.w, yv.w, y2);
        }
        d2 += __shfl_xor(d2, 1, 64); d2 += __shfl_xor(d2, 2, 64);
        y2 += __shfl_xor(y2, 1, 64); y2 += __shfl_xor(y2, 2, 64);
        d_pos = pdist(x2, y2, d2);
    }

    if (dead) {   // only possible for c == 0: write d_pos, zero hinge, exit
        if (lane == 0) {
            wneg[c * NSAMP + s] = 0.0f;
            wpos[s] = d_pos;
        }
        return;
    }

    // negatives: 64 rows of this chunk, 16 rows per pass (one per row-group)
    float hinge_acc = 0.0f;
    #pragma unroll
    for (int it = 0; it < 4; ++it) {
        const int row = c * RPC + it * 16 + rg;
        const float* rowp = seq + (size_t)row * DH + quad * 16;
        float d2 = 0.0f, y2 = 0.0f;
        #pragma unroll
        for (int j = 0; j < 4; ++j) {
            float4 yv = *reinterpret_cast<const float4*>(rowp + j * 4);
            float dx = xv[j].x - yv.x, dy = xv[j].y - yv.y;
            float dz = xv[j].z - yv.z, dw = xv[j].w - yv.w;
            d2 = fmaf(dx, dx, d2); d2 = fmaf(dy, dy, d2);
            d2 = fmaf(dz, dz, d2); d2 = fmaf(dw, dw, d2);
            y2 = fmaf(yv.x, yv.x, y2); y2 = fmaf(yv.y, yv.y, y2);
            y2 = fmaf(yv.z, yv.z, y2); y2 = fmaf(yv.w, yv.w, y2);
        }
        d2 += __shfl_xor(d2, 1, 64); d2 += __shfl_xor(d2, 2, 64);
        y2 += __shfl_xor(y2, 1, 64); y2 += __shfl_xor(y2, 2, 64);
        float dneg = pdist(x2, y2, d2);
        if (row > lt)
            hinge_acc += fmaxf(MARGIN - dneg + d_pos, 0.0f);
    }

    // hinge_acc uniform within each quad; sum across the 16 row-groups
    hinge_acc += __shfl_xor(hinge_acc, 4, 64);
    hinge_acc += __shfl_xor(hinge_acc, 8, 64);
    hinge_acc += __shfl_xor(hinge_acc, 16, 64);
    hinge_acc += __shfl_xor(hinge_acc, 32, 64);

    if (lane == 0) {
        wneg[c * NSAMP + s] = hinge_acc;
        if (c == 0) wpos[s] = d_pos;
    }
}

// 512 threads (8 waves), 1 thread per sample; wneg reads fully coalesced.
__global__ __launch_bounds__(512) void reduce_kernel(
    const float* __restrict__ wneg,
    const float* __restrict__ wpos,
    const int*   __restrict__ align_idx,
    const int*   __restrict__ lookahead_p,
    float* __restrict__ out)
{
    const int tid = threadIdx.x;       // == sample id
    const int lk = lookahead_p[0];

    const int lt = align_idx[tid * 2 + 1] + lk;
    const bool v = (lt >= 0) && (lt < Lc);

    float h = 0.0f;
    #pragma unroll
    for (int c = 0; c < CHUNKS; ++c)
        h += wneg[c * NSAMP + tid];    // consecutive lanes -> consecutive addrs

    const float cnt = v ? (float)(Lc - 1 - lt) : 0.0f;   // #rows > lt
    const float has_neg = (cnt > 0.0f) ? 1.0f : 0.0f;

    float pn = wpos[tid];
    float pv = v ? 1.0f : 0.0f;
    float nn = (h / fmaxf(cnt, 1.0f)) * has_neg;
    float nc = has_neg;

    #pragma unroll
    for (int m = 1; m < 64; m <<= 1) {
        pn += __shfl_xor(pn, m, 64);
        pv += __shfl_xor(pv, m, 64);
        nn += __shfl_xor(nn, m, 64);
        nc += __shfl_xor(nc, m, 64);
    }

    __shared__ float4 sh[8];
    if ((tid & 63) == 0) sh[tid >> 6] = make_float4(pn, pv, nn, nc);
    __syncthreads();
    if (tid == 0) {
        float4 a = sh[0];
        #pragma unroll
        for (int w = 1; w < 8; ++w) {
            a.x += sh[w].x; a.y += sh[w].y; a.z += sh[w].z; a.w += sh[w].w;
        }
        const float pos_term = a.x / fmaxf(a.y, 1.0f);
        const float neg_term = a.z / fmaxf(a.w, 1.0f);
        out[0] = pos_term + NEG_WEIGHT * neg_term;
    }
}

extern "C" void kernel_launch(void* const* d_in, const int* in_sizes, int n_in,
                              void* d_out, int out_size, void* d_ws, size_t ws_size,
                              hipStream_t stream) {
    const float* h_curr    = (const float*)d_in[0];
    const float* demo_h    = (const float*)d_in[1];
    const int*   align_idx = (const int*)d_in[2];
    const int*   lookahead = (const int*)d_in[3];
    float* out  = (float*)d_out;
    float* wneg = (float*)d_ws;                       // CHUNKS*NSAMP floats
    float* wpos = (float*)d_ws + CHUNKS * NSAMP;      // NSAMP floats

    sample_kernel<<<GRID, 256, 0, stream>>>(
        h_curr, demo_h, align_idx, lookahead, wneg, wpos);
    reduce_kernel<<<1, 512, 0, stream>>>(wneg, wpos, align_idx, lookahead, out);
}